// Round 2
// baseline (3875.047 us; speedup 1.0000x reference)
//
#include <hip/hip_runtime.h>
#include <math.h>

#define L_  28
#define H_  1024
#define NH_ 8
#define KVH_ 4
#define HD_ 128
#define I_  3072
#define VC_ 4096
#define B_  4
#define S_  512
#define EPS_ 1e-6f

// ---- workspace layout (float offsets) ----
#define WS_HA   0                      // [4][1024]
#define WS_HB   4096                   // [4][1024]
#define WS_QKVP 8192                   // [16][4][2048]
#define WS_ATTO 139264                 // [4][4][2][8][128]
#define WS_ATTML 172032                // [4][4][2][8][2]
#define WS_OPP  173056                 // [16][4][1024]
#define WS_GUP  238592                 // [8][4][6144]
#define WS_DWP  435200                 // [16][4][1024]
#define WS_HDP  500736                 // [8][4][4096]

__device__ __forceinline__ float wave_reduce_sum(float v) {
    #pragma unroll
    for (int off = 32; off; off >>= 1) v += __shfl_down(v, off);
    return v;
}
__device__ __forceinline__ float wave_reduce_max(float v) {
    #pragma unroll
    for (int off = 32; off; off >>= 1) v = fmaxf(v, __shfl_down(v, off));
    return v;
}

// block=256: reduce 4 per-batch sums across the block. red = LDS float[16].
__device__ __forceinline__ void reduce4(float ss[4], float* red, int t) {
    int lane = t & 63, wv = t >> 6;
    #pragma unroll
    for (int b = 0; b < 4; b++) {
        float v = wave_reduce_sum(ss[b]);
        if (lane == 0) red[b * 4 + wv] = v;
    }
    __syncthreads();
    #pragma unroll
    for (int b = 0; b < 4; b++)
        ss[b] = red[b * 4] + red[b * 4 + 1] + red[b * 4 + 2] + red[b * 4 + 3];
    __syncthreads();
}

// ---------------- embed ----------------
__global__ __launch_bounds__(256) void k_embed(
    const int* __restrict__ cb0, const int* __restrict__ cb1,
    const float* __restrict__ trail, const float* __restrict__ cb0e,
    const float* __restrict__ cpe, float* __restrict__ hA)
{
    int idx = blockIdx.x * 256 + threadIdx.x;   // 0..4095
    int b = idx >> 10, i = idx & 1023;
    float v = cb0e[(size_t)cb0[b] * 1024 + i] + trail[idx];
    #pragma unroll
    for (int j = 0; j < 15; j++)
        v += cpe[((size_t)j * 4096 + cb1[b * 15 + j]) * 1024 + i];
    hA[idx] = v;
}

// ---------------- qkv GEMV partial (fused: finalize h from down-partials, rmsnorm1) ----------------
// grid (8 colblk, 16 ks), block 256
template <bool FIRST>
__global__ __launch_bounds__(256) void k_qkvA(
    const float* __restrict__ hA, float* __restrict__ hB,
    const float* __restrict__ dpart, const float* __restrict__ ln1,
    const float* __restrict__ Wq, const float* __restrict__ Wk,
    const float* __restrict__ Wv, float* __restrict__ qkvp)
{
    __shared__ float xs[4][1024];
    __shared__ float red[16];
    const int t = threadIdx.x;
    float hv[16];
    float ss[4] = {0, 0, 0, 0};
    #pragma unroll
    for (int i = 0; i < 16; i++) {
        int f = t + 256 * i;
        float v = hA[f];
        if (!FIRST) {
            #pragma unroll
            for (int c = 0; c < 16; c++) v += dpart[c * 4096 + f];
        }
        hv[i] = v;
        ss[i >> 2] += v * v;
    }
    if (blockIdx.y == 0) {  // 8 colblks write the finalized h
        hB[blockIdx.x * 512 + t]       = hv[blockIdx.x * 2];
        hB[blockIdx.x * 512 + 256 + t] = hv[blockIdx.x * 2 + 1];
    }
    reduce4(ss, red, t);
    #pragma unroll
    for (int i = 0; i < 16; i++) {
        int f = t + 256 * i, b = i >> 2, k = f & 1023;
        float rms = rsqrtf(ss[b] * (1.f / 1024.f) + EPS_);
        xs[b][k] = hv[i] * rms * ln1[k];
    }
    __syncthreads();
    const int n = blockIdx.x * 256 + t;   // 0..2047
    const float* W; int stride, col;
    if (n < 1024)      { W = Wq; stride = 1024; col = n; }
    else if (n < 1536) { W = Wk; stride = 512;  col = n - 1024; }
    else               { W = Wv; stride = 512;  col = n - 1536; }
    const int k0 = blockIdx.y * 64;
    float acc[4] = {0, 0, 0, 0};
    #pragma unroll 8
    for (int kk = 0; kk < 64; kk++) {
        float w = W[(size_t)(k0 + kk) * stride + col];
        #pragma unroll
        for (int b = 0; b < 4; b++) acc[b] += xs[b][k0 + kk] * w;
    }
    #pragma unroll
    for (int b = 0; b < 4; b++)
        qkvp[(size_t)(blockIdx.y * 4 + b) * 2048 + n] = acc[b];
}

// ---------------- attention flash chunk (fused: qkv reduce, q/k rmsnorm+rope, kv-cache write/copy) ----------------
// grid (16 = b*4+g, 8 = s-chunk), block 256
__global__ __launch_bounds__(256) void k_attn(
    const float* __restrict__ qkvp,
    const float* __restrict__ qnw, const float* __restrict__ knw,
    const float* __restrict__ kin, const float* __restrict__ vin,
    float* __restrict__ kout, float* __restrict__ vout,
    const int* __restrict__ pos,
    float* __restrict__ opart, float* __restrict__ mlpart)
{
    __shared__ float Kl[65][129];
    __shared__ float Vl[65][129];
    __shared__ float ql[2][128];
    __shared__ float sc[2][72];
    __shared__ float red[8];

    const int t = threadIdx.x;
    const int bg = blockIdx.x, b = bg >> 2, g = bg & 3;
    const int c = blockIdx.y;
    const int lane = t & 63;
    const int r = t >> 7, d = t & 127;
    const float scale = 0.088388347648318447f;  // 1/sqrt(128)

    const float posf = (float)pos[b];
    const int j = d & 63;
    const float invf = powf(1.0e6f, -(float)j * (1.0f / 64.0f));
    const float ang = posf * invf;
    const float cs = cosf(ang), sn = sinf(ang);
    const int pd = (d < 64) ? d + 64 : d - 64;

    // q: reduce split-K partials
    float qraw = 0.f;
    {
        const int n = (2 * g + r) * 128 + d;
        #pragma unroll
        for (int ks = 0; ks < 16; ks++) qraw += qkvp[(size_t)(ks * 4 + b) * 2048 + n];
    }
    ql[r][d] = qraw;
    float ssq = wave_reduce_sum(qraw * qraw);
    if (lane == 0) red[t >> 6] = ssq;
    __syncthreads();  // (A)
    const float rms_q = rsqrtf((red[r * 2] + red[r * 2 + 1]) * (1.f / 128.f) + EPS_);
    float qv = qraw * rms_q * qnw[d];
    float qp = ql[r][pd] * rms_q * qnw[pd];
    float qro = qv * cs + ((d < 64) ? -qp : qp) * sn;

    // new k/v (only chunk 7 uses/writes them)
    float kvraw = 0.f;
    if (c == 7) {
        const int base = (t < 128) ? (1024 + g * 128 + d) : (1536 + g * 128 + d);
        #pragma unroll
        for (int ks = 0; ks < 16; ks++) kvraw += qkvp[(size_t)(ks * 4 + b) * 2048 + base];
    }
    float kss = wave_reduce_sum((t < 128) ? kvraw * kvraw : 0.f);
    __syncthreads();  // (B)
    ql[r][d] = qro;
    if (lane == 0 && t < 128) red[t >> 6] = kss;
    if (c == 7) { if (t < 128) Kl[64][d] = kvraw; else Vl[64][d] = kvraw; }
    __syncthreads();  // (C)
    float newkv = 0.f;
    if (c == 7) {
        if (t < 128) {
            const float rms_k = rsqrtf((red[0] + red[1]) * (1.f / 128.f) + EPS_);
            float kv_ = Kl[64][d] * rms_k * knw[d];
            float kp  = Kl[64][pd] * rms_k * knw[pd];
            newkv = kv_ * cs + ((d < 64) ? -kp : kp) * sn;
        } else {
            newkv = Vl[64][d];
        }
    }
    __syncthreads();  // (D)
    const size_t out_bg = (size_t)(b * 4 + g) * (513 * 128);
    if (c == 7) {
        if (t < 128) { Kl[64][d] = newkv; kout[out_bg + 512 * 128 + d] = newkv; }
        else         { Vl[64][d] = newkv; vout[out_bg + 512 * 128 + d] = newkv; }
    }

    // load K/V chunk into LDS + copy to output cache
    const size_t in_bg = (size_t)(b * 4 + g) * (512 * 128);
    const int s0 = c * 64;
    #pragma unroll
    for (int q8 = 0; q8 < 8; q8++) {
        int f4 = t + 256 * q8;      // 0..2047
        int e = f4 * 4;
        int row = e >> 7, d0 = e & 127;
        float4 k4 = *(const float4*)(kin + in_bg + (size_t)(s0 + row) * 128 + d0);
        float4 v4 = *(const float4*)(vin + in_bg + (size_t)(s0 + row) * 128 + d0);
        Kl[row][d0] = k4.x; Kl[row][d0 + 1] = k4.y; Kl[row][d0 + 2] = k4.z; Kl[row][d0 + 3] = k4.w;
        Vl[row][d0] = v4.x; Vl[row][d0 + 1] = v4.y; Vl[row][d0 + 2] = v4.z; Vl[row][d0 + 3] = v4.w;
        *(float4*)(kout + out_bg + (size_t)(s0 + row) * 128 + d0) = k4;
        *(float4*)(vout + out_bg + (size_t)(s0 + row) * 128 + d0) = v4;
    }
    __syncthreads();  // (E)

    // scores for this chunk
    const int nk = (c == 7) ? 65 : 64;
    const int si = d;
    float sv = -1e30f;
    if (si < nk) {
        float a = 0.f;
        #pragma unroll 8
        for (int dd = 0; dd < 128; dd++) a += ql[r][dd] * Kl[si][dd];
        sv = a * scale;
    }
    float mv = wave_reduce_max(sv);
    if (lane == 0) red[t >> 6] = mv;
    __syncthreads();
    const float m = fmaxf(red[r * 2], red[r * 2 + 1]);
    float p = (si < nk) ? expf(sv - m) : 0.f;
    if (si < nk) sc[r][si] = p;
    float lsum = wave_reduce_sum(p);
    __syncthreads();  // m reads done
    if (lane == 0) red[t >> 6] = lsum;
    __syncthreads();
    const float lr = red[r * 2] + red[r * 2 + 1];
    if (d == 0) {
        mlpart[(size_t)(((b * 4 + g) * 2 + r) * 8 + c) * 2 + 0] = m;
        mlpart[(size_t)(((b * 4 + g) * 2 + r) * 8 + c) * 2 + 1] = lr;
    }
    // PV (unnormalized)
    float o = 0.f;
    for (int s2 = 0; s2 < nk; s2++) o += sc[r][s2] * Vl[s2][d];
    opart[(size_t)(((b * 4 + g) * 2 + r) * 8 + c) * 128 + d] = o;
}

// ---------------- o-proj GEMV partial (fused: flash combine) ----------------
// grid (4 colblk, 16 ks), block 256
__global__ __launch_bounds__(256) void k_oprojA(
    const float* __restrict__ opart, const float* __restrict__ mlpart,
    const float* __restrict__ Wo_l, float* __restrict__ opp)
{
    __shared__ float xs[4][64];
    const int t = threadIdx.x;
    const int ks = blockIdx.y;
    const int n0 = ks * 64;
    {
        const int b = t >> 6, dd = t & 63;
        const int n = n0 + dd;
        const int head = n >> 7, dh = n & 127;
        const int g = head >> 1, rr = head & 1;
        const size_t mlb = (size_t)(((b * 4 + g) * 2 + rr) * 8) * 2;
        float mc[8], lc[8], M = -1e30f;
        #pragma unroll
        for (int cc = 0; cc < 8; cc++) {
            mc[cc] = mlpart[mlb + cc * 2]; lc[cc] = mlpart[mlb + cc * 2 + 1];
            M = fmaxf(M, mc[cc]);
        }
        float Ls = 0.f, o = 0.f;
        const size_t ob = (size_t)(((b * 4 + g) * 2 + rr) * 8) * 128 + dh;
        #pragma unroll
        for (int cc = 0; cc < 8; cc++) {
            float w = expf(mc[cc] - M);
            Ls += lc[cc] * w;
            o += opart[ob + cc * 128] * w;
        }
        xs[b][dd] = o / Ls;
    }
    __syncthreads();
    const int col = blockIdx.x * 256 + t;
    float acc[4] = {0, 0, 0, 0};
    #pragma unroll 8
    for (int kk = 0; kk < 64; kk++) {
        float w = Wo_l[(size_t)(n0 + kk) * 1024 + col];
        #pragma unroll
        for (int b = 0; b < 4; b++) acc[b] += xs[b][kk] * w;
    }
    #pragma unroll
    for (int b = 0; b < 4; b++) opp[(size_t)(ks * 4 + b) * 1024 + col] = acc[b];
}

// ---------------- gate/up GEMV partial (fused: o-proj reduce + residual + rmsnorm2) ----------------
// grid (12 colblk, 8 ks), block 256
__global__ __launch_bounds__(256) void k_gateupA(
    const float* __restrict__ hB, float* __restrict__ h1out,
    const float* __restrict__ opp, const float* __restrict__ ln2,
    const float* __restrict__ Wg_l, const float* __restrict__ Wu_l,
    float* __restrict__ gup)
{
    __shared__ float xs[4][1024];
    __shared__ float red[16];
    const int t = threadIdx.x;
    float hv[16];
    float ss[4] = {0, 0, 0, 0};
    #pragma unroll
    for (int i = 0; i < 16; i++) {
        int f = t + 256 * i;
        float v = hB[f];
        #pragma unroll
        for (int cc = 0; cc < 16; cc++) v += opp[cc * 4096 + f];
        hv[i] = v;
        ss[i >> 2] += v * v;
    }
    if (blockIdx.y == 0 && blockIdx.x < 8) {
        h1out[blockIdx.x * 512 + t]       = hv[blockIdx.x * 2];
        h1out[blockIdx.x * 512 + 256 + t] = hv[blockIdx.x * 2 + 1];
    }
    reduce4(ss, red, t);
    #pragma unroll
    for (int i = 0; i < 16; i++) {
        int f = t + 256 * i, b = i >> 2, k = f & 1023;
        float rms = rsqrtf(ss[b] * (1.f / 1024.f) + EPS_);
        xs[b][k] = hv[i] * rms * ln2[k];
    }
    __syncthreads();
    const int n = blockIdx.x * 256 + t;
    const int k0 = blockIdx.y * 128;
    float ag[4] = {0, 0, 0, 0}, au[4] = {0, 0, 0, 0};
    #pragma unroll 4
    for (int kk = 0; kk < 128; kk++) {
        float wg = Wg_l[(size_t)(k0 + kk) * 3072 + n];
        float wu = Wu_l[(size_t)(k0 + kk) * 3072 + n];
        #pragma unroll
        for (int b = 0; b < 4; b++) {
            ag[b] += xs[b][k0 + kk] * wg;
            au[b] += xs[b][k0 + kk] * wu;
        }
    }
    #pragma unroll
    for (int b = 0; b < 4; b++) {
        gup[(size_t)(blockIdx.y * 4 + b) * 6144 + n]        = ag[b];
        gup[(size_t)(blockIdx.y * 4 + b) * 6144 + 3072 + n] = au[b];
    }
}

// ---------------- down GEMV partial (fused: gate/up reduce + SiLU) ----------------
// grid (4 colblk, 16 ks), block 256
__global__ __launch_bounds__(256) void k_downA(
    const float* __restrict__ gup, const float* __restrict__ Wd_l,
    float* __restrict__ dwp)
{
    __shared__ float xs[4][192];
    const int t = threadIdx.x;
    const int ks = blockIdx.y;
    const int k0 = ks * 192;
    #pragma unroll
    for (int jj = 0; jj < 3; jj++) {
        int v = t + 256 * jj;           // 0..767
        int b = v / 192, kk = v - b * 192;
        float gg = 0.f, uu = 0.f;
        #pragma unroll
        for (int cc = 0; cc < 8; cc++) {
            gg += gup[(size_t)(cc * 4 + b) * 6144 + k0 + kk];
            uu += gup[(size_t)(cc * 4 + b) * 6144 + 3072 + k0 + kk];
        }
        xs[b][kk] = gg / (1.f + expf(-gg)) * uu;
    }
    __syncthreads();
    const int col = blockIdx.x * 256 + t;
    float acc[4] = {0, 0, 0, 0};
    #pragma unroll 8
    for (int kk = 0; kk < 192; kk++) {
        float w = Wd_l[(size_t)(k0 + kk) * 1024 + col];
        #pragma unroll
        for (int b = 0; b < 4; b++) acc[b] += xs[b][kk] * w;
    }
    #pragma unroll
    for (int b = 0; b < 4; b++) dwp[(size_t)(ks * 4 + b) * 1024 + col] = acc[b];
}

// ---------------- final: finalize h + rmsnorm(norm_w) + head GEMV partial + past_hidden ----------------
// grid (16 colblk, 8 ks), block 256
__global__ __launch_bounds__(256) void k_finalA(
    const float* __restrict__ hA, const float* __restrict__ dwp,
    const float* __restrict__ normw, const float* __restrict__ headw,
    float* __restrict__ hdp, float* __restrict__ past)
{
    __shared__ float xs[4][1024];
    __shared__ float red[16];
    const int t = threadIdx.x;
    float hv[16];
    float ss[4] = {0, 0, 0, 0};
    #pragma unroll
    for (int i = 0; i < 16; i++) {
        int f = t + 256 * i;
        float v = hA[f];
        #pragma unroll
        for (int cc = 0; cc < 16; cc++) v += dwp[cc * 4096 + f];
        hv[i] = v;
        ss[i >> 2] += v * v;
    }
    reduce4(ss, red, t);
    float xn[16];
    #pragma unroll
    for (int i = 0; i < 16; i++) {
        int f = t + 256 * i, b = i >> 2, k = f & 1023;
        float rms = rsqrtf(ss[b] * (1.f / 1024.f) + EPS_);
        xn[i] = hv[i] * rms * normw[k];
        xs[b][k] = xn[i];
    }
    if (blockIdx.y == 0 && blockIdx.x < 8) {
        past[blockIdx.x * 512 + t]       = xn[blockIdx.x * 2];
        past[blockIdx.x * 512 + 256 + t] = xn[blockIdx.x * 2 + 1];
    }
    __syncthreads();
    const int n = blockIdx.x * 256 + t;   // 0..4095
    const int k0 = blockIdx.y * 128;
    float acc[4] = {0, 0, 0, 0};
    #pragma unroll 4
    for (int kk = 0; kk < 128; kk++) {
        float w = headw[(size_t)(k0 + kk) * 4096 + n];
        #pragma unroll
        for (int b = 0; b < 4; b++) acc[b] += xs[b][k0 + kk] * w;
    }
    #pragma unroll
    for (int b = 0; b < 4; b++) hdp[(size_t)(blockIdx.y * 4 + b) * 4096 + n] = acc[b];
}

__global__ __launch_bounds__(256) void k_finalB(
    const float* __restrict__ hdp, float* __restrict__ logits)
{
    int idx = blockIdx.x * 256 + threadIdx.x;   // 0..16383
    float v = 0.f;
    #pragma unroll
    for (int c = 0; c < 8; c++) v += hdp[c * 16384 + idx];
    logits[idx] = v;
}

extern "C" void kernel_launch(void* const* d_in, const int* in_sizes, int n_in,
                              void* d_out, int out_size, void* d_ws, size_t ws_size,
                              hipStream_t stream)
{
    const int*   cb0   = (const int*)d_in[0];
    const int*   cb1   = (const int*)d_in[1];
    const float* trail = (const float*)d_in[2];
    const float* kvin  = (const float*)d_in[3];
    const int*   pos   = (const int*)d_in[4];
    const float* cb0e  = (const float*)d_in[5];
    const float* cpe   = (const float*)d_in[6];
    const float* Wq    = (const float*)d_in[7];
    const float* Wk    = (const float*)d_in[8];
    const float* Wv    = (const float*)d_in[9];
    const float* Wo    = (const float*)d_in[10];
    const float* qnw   = (const float*)d_in[11];
    const float* knw   = (const float*)d_in[12];
    const float* ln1   = (const float*)d_in[13];
    const float* ln2   = (const float*)d_in[14];
    const float* Wg    = (const float*)d_in[15];
    const float* Wu    = (const float*)d_in[16];
    const float* Wd    = (const float*)d_in[17];
    const float* normw = (const float*)d_in[18];
    const float* headw = (const float*)d_in[19];

    float* out    = (float*)d_out;
    float* logits = out;
    float* kvout  = out + 16384;
    float* past   = out + 16384 + (size_t)2 * L_ * B_ * KVH_ * (S_ + 1) * HD_;
    float* ws = (float*)d_ws;

    float* hA   = ws + WS_HA;
    float* hB   = ws + WS_HB;
    float* qkvp = ws + WS_QKVP;
    float* atto = ws + WS_ATTO;
    float* atml = ws + WS_ATTML;
    float* opp  = ws + WS_OPP;
    float* gup  = ws + WS_GUP;
    float* dwp  = ws + WS_DWP;
    float* hdp  = ws + WS_HDP;

    const size_t IN_PLANE  = (size_t)B_ * KVH_ * S_ * HD_;
    const size_t OUT_PLANE = (size_t)B_ * KVH_ * (S_ + 1) * HD_;

    k_embed<<<16, 256, 0, stream>>>(cb0, cb1, trail, cb0e, cpe, hA);

    for (int l = 0; l < L_; l++) {
        if (l == 0)
            k_qkvA<true><<<dim3(8, 16), 256, 0, stream>>>(
                hA, hB, dwp, ln1 + (size_t)l * H_,
                Wq + (size_t)l * H_ * 1024, Wk + (size_t)l * H_ * 512,
                Wv + (size_t)l * H_ * 512, qkvp);
        else
            k_qkvA<false><<<dim3(8, 16), 256, 0, stream>>>(
                hA, hB, dwp, ln1 + (size_t)l * H_,
                Wq + (size_t)l * H_ * 1024, Wk + (size_t)l * H_ * 512,
                Wv + (size_t)l * H_ * 512, qkvp);
        k_attn<<<dim3(16, 8), 256, 0, stream>>>(
            qkvp, qnw + (size_t)l * HD_, knw + (size_t)l * HD_,
            kvin + (size_t)(2 * l) * IN_PLANE, kvin + (size_t)(2 * l + 1) * IN_PLANE,
            kvout + (size_t)(2 * l) * OUT_PLANE, kvout + (size_t)(2 * l + 1) * OUT_PLANE,
            pos, atto, atml);
        k_oprojA<<<dim3(4, 16), 256, 0, stream>>>(
            atto, atml, Wo + (size_t)l * 1024 * H_, opp);
        k_gateupA<<<dim3(12, 8), 256, 0, stream>>>(
            hB, hA, opp, ln2 + (size_t)l * H_,
            Wg + (size_t)l * H_ * I_, Wu + (size_t)l * H_ * I_, gup);
        k_downA<<<dim3(4, 16), 256, 0, stream>>>(
            gup, Wd + (size_t)l * I_ * H_, dwp);
    }
    k_finalA<<<dim3(16, 8), 256, 0, stream>>>(hA, dwp, normw, headw, hdp, past);
    k_finalB<<<64, 256, 0, stream>>>(hdp, logits);
}

// Round 3
// 1190.410 us; speedup vs baseline: 3.2552x; 3.2552x over previous
//
#include <hip/hip_runtime.h>
#include <math.h>

#define L_  28
#define H_  1024
#define NH_ 8
#define KVH_ 4
#define HD_ 128
#define I_  3072
#define VC_ 4096
#define B_  4
#define S_  512
#define EPS_ 1e-6f

// ---- workspace layout (float offsets) ----
#define WS_HA   0                       // [4][1024] residual h (even stages)
#define WS_HB   4096                    // [4][1024] residual h (odd stages)
#define WS_X1   8192                    // [4][1024] rmsnorm1 out
#define WS_X2   12288                   // [4][1024] rmsnorm2 out
#define WS_XF   16384                   // [4][1024] final norm out
#define WS_QKVP 20480                   // [32][4][2048]
#define WS_ATTO 282624                  // [16 bg][2 r][16 c][128]
#define WS_ATML 348160                  // [16 bg][2 r][16 c][2]
#define WS_OPP  349184                  // [32][4][1024]
#define WS_GUP  480256                  // [32][4][6144]
#define WS_DWP  1266688                 // [48][4][1024]
#define WS_HDP  1463296                 // [32][4][4096]
// end: 1987584 floats = 7.95 MB

__device__ __forceinline__ float wave_reduce_sum(float v) {
    #pragma unroll
    for (int off = 32; off; off >>= 1) v += __shfl_down(v, off);
    return v;
}
__device__ __forceinline__ float wave_reduce_max(float v) {
    #pragma unroll
    for (int off = 32; off; off >>= 1) v = fmaxf(v, __shfl_down(v, off));
    return v;
}

// ---------------- embed ----------------
__global__ __launch_bounds__(256) void k_embed(
    const int* __restrict__ cb0, const int* __restrict__ cb1,
    const float* __restrict__ trail, const float* __restrict__ cb0e,
    const float* __restrict__ cpe, float* __restrict__ hA)
{
    int idx = blockIdx.x * 256 + threadIdx.x;   // 0..4095
    int b = idx >> 10, i = idx & 1023;
    float v = cb0e[(size_t)cb0[b] * 1024 + i] + trail[idx];
    #pragma unroll
    for (int j = 0; j < 15; j++)
        v += cpe[((size_t)j * 4096 + cb1[b * 15 + j]) * 1024 + i];
    hA[idx] = v;
}

// ---------------- norm: h = base + sum(P partial chunks); x = rmsnorm(h)*w ----------------
// grid 4 (batch), block 1024
template<int P>
__global__ __launch_bounds__(1024) void k_norm(
    const float* __restrict__ base, const float* __restrict__ part,
    const float* __restrict__ w, float* __restrict__ hnew,
    float* __restrict__ xout, float* __restrict__ xout2)
{
    __shared__ float red[16];
    const int b = blockIdx.x, k = threadIdx.x;
    float v = base[b * 1024 + k];
    #pragma unroll
    for (int c = 0; c < P; c++) v += part[((size_t)c * 4 + b) * 1024 + k];
    hnew[b * 1024 + k] = v;
    float ss = wave_reduce_sum(v * v);
    if ((k & 63) == 0) red[k >> 6] = ss;
    __syncthreads();
    float tot = 0.f;
    #pragma unroll
    for (int i = 0; i < 16; i++) tot += red[i];
    const float rms = rsqrtf(tot * (1.f / 1024.f) + EPS_);
    const float x = v * rms * w[k];
    xout[b * 1024 + k] = x;
    if (xout2) xout2[b * 1024 + k] = x;
}

// ---------------- GEMV core: block = 256 thr (4 waves), 256 cols, RPC rows ----------------
// xsl: LDS [RPC][4] (row-major, 4 batches). accbuf: LDS float4[1024] (16 KB).
// Writes pp[(ks*4+b)*NTOT + colblk*256 + col].
template<int RPC, int NTOT>
__device__ __forceinline__ void gemv_tail(
    const float* __restrict__ W, int ldw, int wcol0, int k0,
    const float* __restrict__ xsl, float4* __restrict__ accbuf,
    float* __restrict__ pp, int colblk, int ks)
{
    const int t = threadIdx.x;
    const int wv = t >> 6, lane = t & 63;
    constexpr int RPW = RPC / 4;                  // rows per wave
    const float4* xs4 = (const float4*)xsl;
    float4 a0 = {0,0,0,0}, a1 = {0,0,0,0}, a2 = {0,0,0,0}, a3 = {0,0,0,0};
    const float* Wp = W + (size_t)(k0 + wv * RPW) * ldw + wcol0 + lane * 4;
    #pragma unroll 8
    for (int i = 0; i < RPW; i++) {
        float4 wvv = *(const float4*)(Wp + (size_t)i * ldw);
        float4 xb = xs4[wv * RPW + i];
        a0.x += wvv.x * xb.x; a0.y += wvv.y * xb.x; a0.z += wvv.z * xb.x; a0.w += wvv.w * xb.x;
        a1.x += wvv.x * xb.y; a1.y += wvv.y * xb.y; a1.z += wvv.z * xb.y; a1.w += wvv.w * xb.y;
        a2.x += wvv.x * xb.z; a2.y += wvv.y * xb.z; a2.z += wvv.z * xb.z; a2.w += wvv.w * xb.z;
        a3.x += wvv.x * xb.w; a3.y += wvv.y * xb.w; a3.z += wvv.z * xb.w; a3.w += wvv.w * xb.w;
    }
    accbuf[(wv * 64 + lane) * 4 + 0] = a0;
    accbuf[(wv * 64 + lane) * 4 + 1] = a1;
    accbuf[(wv * 64 + lane) * 4 + 2] = a2;
    accbuf[(wv * 64 + lane) * 4 + 3] = a3;
    __syncthreads();
    const int l2 = t >> 2, b2 = t & 3;
    float4 s0 = accbuf[(0 * 64 + l2) * 4 + b2];
    float4 s1 = accbuf[(1 * 64 + l2) * 4 + b2];
    float4 s2 = accbuf[(2 * 64 + l2) * 4 + b2];
    float4 s3 = accbuf[(3 * 64 + l2) * 4 + b2];
    float4 s;
    s.x = s0.x + s1.x + s2.x + s3.x;
    s.y = s0.y + s1.y + s2.y + s3.y;
    s.z = s0.z + s1.z + s2.z + s3.z;
    s.w = s0.w + s1.w + s2.w + s3.w;
    *(float4*)(pp + ((size_t)ks * 4 + b2) * NTOT + colblk * 256 + l2 * 4) = s;
}

// ---------------- qkv GEMV: grid (8 colblk, 32 ks) ----------------
__global__ __launch_bounds__(256) void k_qkv(
    const float* __restrict__ x1,
    const float* __restrict__ Wq, const float* __restrict__ Wk,
    const float* __restrict__ Wv, float* __restrict__ qkvp)
{
    __shared__ float xsl[128];
    __shared__ float4 accbuf[1024];
    const int t = threadIdx.x;
    const int ks = blockIdx.y, k0 = ks * 32, cb = blockIdx.x;
    if (t < 128) { int kk = t & 31, b = t >> 5; xsl[kk * 4 + b] = x1[b * 1024 + k0 + kk]; }
    __syncthreads();
    const float* W; int ldw, wcol0;
    if (cb < 4)      { W = Wq; ldw = 1024; wcol0 = cb * 256; }
    else if (cb < 6) { W = Wk; ldw = 512;  wcol0 = (cb - 4) * 256; }
    else             { W = Wv; ldw = 512;  wcol0 = (cb - 6) * 256; }
    gemv_tail<32, 2048>(W, ldw, wcol0, k0, xsl, accbuf, qkvp, cb, ks);
}

// ---------------- attention flash chunk: grid (16 bg, 16 c), block 256 ----------------
__global__ __launch_bounds__(256) void k_attn(
    const float* __restrict__ qkvp,
    const float* __restrict__ qnw, const float* __restrict__ knw,
    const float* __restrict__ kin, const float* __restrict__ vin,
    float* __restrict__ kout, float* __restrict__ vout,
    const int* __restrict__ pos,
    float* __restrict__ opart, float* __restrict__ mlpart)
{
    __shared__ float Kl[33][129];
    __shared__ float Vl[33][129];
    __shared__ float ql[2][128];
    __shared__ float sc[2][36];
    __shared__ float red[8];

    const int t = threadIdx.x;
    const int bg = blockIdx.x, b = bg >> 2, g = bg & 3;
    const int c = blockIdx.y;           // 0..15
    const int lane = t & 63;
    const int r = t >> 7, d = t & 127;
    const float scale = 0.088388347648318447f;  // 1/sqrt(128)

    const float posf = (float)pos[b];
    const int j = d & 63;
    const float invf = powf(1.0e6f, -(float)j * (1.0f / 64.0f));
    const float ang = posf * invf;
    const float cs = cosf(ang), sn = sinf(ang);
    const int pd = (d < 64) ? d + 64 : d - 64;

    // q: reduce 32 split-K chunks
    float qraw = 0.f;
    {
        const int n = (2 * g + r) * 128 + d;
        #pragma unroll
        for (int cc = 0; cc < 32; cc++) qraw += qkvp[((size_t)cc * 4 + b) * 2048 + n];
    }
    ql[r][d] = qraw;
    float ssq = wave_reduce_sum(qraw * qraw);
    if (lane == 0) red[t >> 6] = ssq;
    __syncthreads();  // (A)
    const float rms_q = rsqrtf((red[r * 2] + red[r * 2 + 1]) * (1.f / 128.f) + EPS_);
    float qv = qraw * rms_q * qnw[d];
    float qp = ql[r][pd] * rms_q * qnw[pd];
    float qro = qv * cs + ((d < 64) ? -qp : qp) * sn;

    // new k/v: only chunk 15
    float kvraw = 0.f;
    if (c == 15) {
        const int base = (t < 128) ? (1024 + g * 128 + d) : (1536 + g * 128 + d);
        #pragma unroll
        for (int cc = 0; cc < 32; cc++) kvraw += qkvp[((size_t)cc * 4 + b) * 2048 + base];
    }
    float kss = wave_reduce_sum((t < 128) ? kvraw * kvraw : 0.f);
    __syncthreads();  // (B)
    ql[r][d] = qro;
    if (lane == 0 && t < 128) red[t >> 6] = kss;
    if (c == 15) { if (t < 128) Kl[32][d] = kvraw; else Vl[32][d] = kvraw; }
    __syncthreads();  // (C)
    float newkv = 0.f;
    if (c == 15) {
        if (t < 128) {
            const float rms_k = rsqrtf((red[0] + red[1]) * (1.f / 128.f) + EPS_);
            float kv_ = Kl[32][d] * rms_k * knw[d];
            float kp  = Kl[32][pd] * rms_k * knw[pd];
            newkv = kv_ * cs + ((d < 64) ? -kp : kp) * sn;
        } else {
            newkv = Vl[32][d];
        }
    }
    __syncthreads();  // (D)
    const size_t out_bg = (size_t)bg * (513 * 128);
    if (c == 15) {
        if (t < 128) { Kl[32][d] = newkv; kout[out_bg + 512 * 128 + d] = newkv; }
        else         { Vl[32][d] = newkv; vout[out_bg + 512 * 128 + d] = newkv; }
    }

    // KV tile (32 keys) load into LDS + copy to output cache (float4)
    const size_t in_bg = (size_t)bg * (512 * 128);
    const int s0 = c * 32;
    #pragma unroll
    for (int i = 0; i < 4; i++) {
        int f4 = i * 256 + t;           // 0..1023 float4s
        int row = f4 >> 5, d0 = (f4 & 31) * 4;
        float4 k4 = *(const float4*)(kin + in_bg + (size_t)(s0 + row) * 128 + d0);
        float4 v4 = *(const float4*)(vin + in_bg + (size_t)(s0 + row) * 128 + d0);
        Kl[row][d0] = k4.x; Kl[row][d0 + 1] = k4.y; Kl[row][d0 + 2] = k4.z; Kl[row][d0 + 3] = k4.w;
        Vl[row][d0] = v4.x; Vl[row][d0 + 1] = v4.y; Vl[row][d0 + 2] = v4.z; Vl[row][d0 + 3] = v4.w;
        *(float4*)(kout + out_bg + (size_t)(s0 + row) * 128 + d0) = k4;
        *(float4*)(vout + out_bg + (size_t)(s0 + row) * 128 + d0) = v4;
    }
    __syncthreads();  // (E)

    // scores
    const int nk = (c == 15) ? 33 : 32;
    const int si = d;
    float sv = -1e30f;
    if (si < nk) {
        float a = 0.f;
        #pragma unroll 8
        for (int dd = 0; dd < 128; dd++) a += ql[r][dd] * Kl[si][dd];
        sv = a * scale;
    }
    float mv = wave_reduce_max(sv);
    if (lane == 0) red[t >> 6] = mv;
    __syncthreads();
    const float m = fmaxf(red[r * 2], red[r * 2 + 1]);
    float p = (si < nk) ? expf(sv - m) : 0.f;
    if (si < nk) sc[r][si] = p;
    float lsum = wave_reduce_sum(p);
    __syncthreads();
    if (lane == 0) red[t >> 6] = lsum;
    __syncthreads();
    const float lr = red[r * 2] + red[r * 2 + 1];
    if (d == 0) {
        mlpart[(size_t)((bg * 2 + r) * 16 + c) * 2 + 0] = m;
        mlpart[(size_t)((bg * 2 + r) * 16 + c) * 2 + 1] = lr;
    }
    float o = 0.f;
    for (int s2 = 0; s2 < nk; s2++) o += sc[r][s2] * Vl[s2][d];
    opart[(size_t)((bg * 2 + r) * 16 + c) * 128 + d] = o;
}

// ---------------- o-proj GEMV (fused flash combine): grid (4 colblk, 32 ks) ----------------
__global__ __launch_bounds__(256) void k_oproj(
    const float* __restrict__ atto, const float* __restrict__ atml,
    const float* __restrict__ Wo_l, float* __restrict__ opp)
{
    __shared__ float xsl[128];
    __shared__ float4 accbuf[1024];
    const int t = threadIdx.x;
    const int ks = blockIdx.y, k0 = ks * 32;
    if (t < 128) {
        const int kk = t & 31, b = t >> 5;
        const int nrow = k0 + kk;
        const int head = nrow >> 7, dh = nrow & 127;
        const int g = head >> 1, rr = head & 1;
        const size_t base = (size_t)((b * 4 + g) * 2 + rr) * 16;
        float mc[16], lc[16], M = -1e30f;
        #pragma unroll
        for (int cc = 0; cc < 16; cc++) {
            mc[cc] = atml[(base + cc) * 2];
            lc[cc] = atml[(base + cc) * 2 + 1];
            M = fmaxf(M, mc[cc]);
        }
        float Ls = 0.f, o = 0.f;
        #pragma unroll
        for (int cc = 0; cc < 16; cc++) {
            float wch = expf(mc[cc] - M);
            Ls += lc[cc] * wch;
            o += atto[(base + cc) * 128 + dh] * wch;
        }
        xsl[kk * 4 + b] = o / Ls;
    }
    __syncthreads();
    gemv_tail<32, 1024>(Wo_l, 1024, blockIdx.x * 256, k0, xsl, accbuf, opp, blockIdx.x, ks);
}

// ---------------- gate/up GEMV: grid (24 colblk, 32 ks) ----------------
__global__ __launch_bounds__(256) void k_gateup(
    const float* __restrict__ x2,
    const float* __restrict__ Wg_l, const float* __restrict__ Wu_l,
    float* __restrict__ gup)
{
    __shared__ float xsl[128];
    __shared__ float4 accbuf[1024];
    const int t = threadIdx.x;
    const int ks = blockIdx.y, k0 = ks * 32, cb = blockIdx.x;
    if (t < 128) { int kk = t & 31, b = t >> 5; xsl[kk * 4 + b] = x2[b * 1024 + k0 + kk]; }
    __syncthreads();
    const float* W; int wcol0;
    if (cb < 12) { W = Wg_l; wcol0 = cb * 256; }
    else         { W = Wu_l; wcol0 = (cb - 12) * 256; }
    gemv_tail<32, 6144>(W, 3072, wcol0, k0, xsl, accbuf, gup, cb, ks);
}

// ---------------- down GEMV (fused gup reduce + SiLU): grid (4 colblk, 48 ks) ----------------
__global__ __launch_bounds__(256) void k_down(
    const float* __restrict__ gup, const float* __restrict__ Wd_l,
    float* __restrict__ dwp)
{
    __shared__ float xsl[256];
    __shared__ float4 accbuf[1024];
    const int t = threadIdx.x;
    const int ks = blockIdx.y, k0 = ks * 64;
    {
        const int b = t >> 6, kk = t & 63;
        float gg = 0.f, uu = 0.f;
        #pragma unroll
        for (int cc = 0; cc < 32; cc++) {
            gg += gup[((size_t)cc * 4 + b) * 6144 + k0 + kk];
            uu += gup[((size_t)cc * 4 + b) * 6144 + 3072 + k0 + kk];
        }
        xsl[kk * 4 + b] = gg / (1.f + expf(-gg)) * uu;
    }
    __syncthreads();
    gemv_tail<64, 1024>(Wd_l, 1024, blockIdx.x * 256, k0, xsl, accbuf, dwp, blockIdx.x, ks);
}

// ---------------- head GEMV: grid (16 colblk, 32 ks) ----------------
__global__ __launch_bounds__(256) void k_head(
    const float* __restrict__ xf, const float* __restrict__ headw,
    float* __restrict__ hdp)
{
    __shared__ float xsl[128];
    __shared__ float4 accbuf[1024];
    const int t = threadIdx.x;
    const int ks = blockIdx.y, k0 = ks * 32, cb = blockIdx.x;
    if (t < 128) { int kk = t & 31, b = t >> 5; xsl[kk * 4 + b] = xf[b * 1024 + k0 + kk]; }
    __syncthreads();
    gemv_tail<32, 4096>(headw, 4096, cb * 256, k0, xsl, accbuf, hdp, cb, ks);
}

// ---------------- logits reduce: grid 16 ----------------
__global__ __launch_bounds__(256) void k_logits(
    const float* __restrict__ hdp, float* __restrict__ logits)
{
    int t4 = blockIdx.x * 256 + threadIdx.x;   // 0..4095 float4s
    int b = t4 >> 10, n4 = t4 & 1023;
    float4 s = {0.f, 0.f, 0.f, 0.f};
    #pragma unroll
    for (int c = 0; c < 32; c++) {
        float4 v = *(const float4*)(hdp + ((size_t)c * 4 + b) * 4096 + n4 * 4);
        s.x += v.x; s.y += v.y; s.z += v.z; s.w += v.w;
    }
    *(float4*)(logits + (size_t)b * 4096 + n4 * 4) = s;
}

extern "C" void kernel_launch(void* const* d_in, const int* in_sizes, int n_in,
                              void* d_out, int out_size, void* d_ws, size_t ws_size,
                              hipStream_t stream)
{
    const int*   cb0   = (const int*)d_in[0];
    const int*   cb1   = (const int*)d_in[1];
    const float* trail = (const float*)d_in[2];
    const float* kvin  = (const float*)d_in[3];
    const int*   pos   = (const int*)d_in[4];
    const float* cb0e  = (const float*)d_in[5];
    const float* cpe   = (const float*)d_in[6];
    const float* Wq    = (const float*)d_in[7];
    const float* Wk    = (const float*)d_in[8];
    const float* Wv    = (const float*)d_in[9];
    const float* Wo    = (const float*)d_in[10];
    const float* qnw   = (const float*)d_in[11];
    const float* knw   = (const float*)d_in[12];
    const float* ln1   = (const float*)d_in[13];
    const float* ln2   = (const float*)d_in[14];
    const float* Wg    = (const float*)d_in[15];
    const float* Wu    = (const float*)d_in[16];
    const float* Wd    = (const float*)d_in[17];
    const float* normw = (const float*)d_in[18];
    const float* headw = (const float*)d_in[19];

    float* out    = (float*)d_out;
    float* logits = out;
    float* kvout  = out + 16384;
    float* past   = out + 16384 + (size_t)2 * L_ * B_ * KVH_ * (S_ + 1) * HD_;
    float* ws = (float*)d_ws;

    float* hA   = ws + WS_HA;
    float* hB   = ws + WS_HB;
    float* x1   = ws + WS_X1;
    float* x2   = ws + WS_X2;
    float* xf   = ws + WS_XF;
    float* qkvp = ws + WS_QKVP;
    float* atto = ws + WS_ATTO;
    float* atml = ws + WS_ATML;
    float* opp  = ws + WS_OPP;
    float* gup  = ws + WS_GUP;
    float* dwp  = ws + WS_DWP;
    float* hdp  = ws + WS_HDP;

    const size_t IN_PLANE  = (size_t)B_ * KVH_ * S_ * HD_;
    const size_t OUT_PLANE = (size_t)B_ * KVH_ * (S_ + 1) * HD_;

    k_embed<<<16, 256, 0, stream>>>(cb0, cb1, trail, cb0e, cpe, hA);

    for (int l = 0; l < L_; l++) {
        // norm1: h(hA + dwp) -> hB, x1
        if (l == 0)
            k_norm<0><<<4, 1024, 0, stream>>>(hA, dwp, ln1 + (size_t)l * H_, hB, x1, nullptr);
        else
            k_norm<48><<<4, 1024, 0, stream>>>(hA, dwp, ln1 + (size_t)l * H_, hB, x1, nullptr);
        k_qkv<<<dim3(8, 32), 256, 0, stream>>>(
            x1, Wq + (size_t)l * H_ * 1024, Wk + (size_t)l * H_ * 512,
            Wv + (size_t)l * H_ * 512, qkvp);
        k_attn<<<dim3(16, 16), 256, 0, stream>>>(
            qkvp, qnw + (size_t)l * HD_, knw + (size_t)l * HD_,
            kvin + (size_t)(2 * l) * IN_PLANE, kvin + (size_t)(2 * l + 1) * IN_PLANE,
            kvout + (size_t)(2 * l) * OUT_PLANE, kvout + (size_t)(2 * l + 1) * OUT_PLANE,
            pos, atto, atml);
        k_oproj<<<dim3(4, 32), 256, 0, stream>>>(
            atto, atml, Wo + (size_t)l * 1024 * H_, opp);
        // norm2: h(hB + opp) -> hA, x2
        k_norm<32><<<4, 1024, 0, stream>>>(hB, opp, ln2 + (size_t)l * H_, hA, x2, nullptr);
        k_gateup<<<dim3(24, 32), 256, 0, stream>>>(
            x2, Wg + (size_t)l * H_ * I_, Wu + (size_t)l * H_ * I_, gup);
        k_down<<<dim3(4, 48), 256, 0, stream>>>(
            gup, Wd + (size_t)l * I_ * H_, dwp);
    }
    // final norm: h(hA + dwp) -> (hB dummy), xf + past_hidden
    k_norm<48><<<4, 1024, 0, stream>>>(hA, dwp, normw, hB, xf, past);
    k_head<<<dim3(16, 32), 256, 0, stream>>>(xf, headw, hdp);
    k_logits<<<16, 256, 0, stream>>>(hdp, logits);
}